// Round 4
// baseline (52662.451 us; speedup 1.0000x reference)
//
#include <hip/hip_runtime.h>
#include <math.h>
#include <float.h>

// VQ-VAE VectorQuantizer forward, MI355X (gfx950).
// R4: bf16-MFMA candidate filter + exact fp32 rescore.
//   x: [16,4096,256] f32 (N=65536 rows), embedding: [4096,256] f32 (K=4096).
//   out: [0,16777216) quantized_st | [Q_OFF,+65536) indices(float) | [L_OFF] loss
//
// Bit-exactness strategy (R1-proven components kept):
//   - reference score bits = fl(xnorm - 2*serial_dot); AVX2-tree xnorm; ties -> lowest idx.
//   - MFMA scores s~ satisfy |s~-s| <= E = 2*2^-6.8*||x||2*max||e||2 + 1.2e-4 (RNE bf16
//     conversion 2^-8/elem, exact bf16 products, fp32 accum, epilogue rounding).
//   - collect codes with s~ <= running_min + T, T = 4x bound >= 2E  => true argmin always
//     collected; exact-rescore candidates with R1's serial fmaf chain; atomicMin on
//     packed (orderable_score<<32|idx) u64 reproduces argmin-with-lowest-index-ties.
//
// Scratch (inside out[0..16.7M), overwritten by k_output at the end):
//   xb bf16 [0..8388608) | eb bf16 [8388608..8912896) | xnorm [8912896..)
//   emax2 @8978432 | BEST u64 @8978440 (8B-aligned)

typedef unsigned int u32; typedef unsigned long long u64; typedef unsigned short u16;
typedef __attribute__((ext_vector_type(8))) short bf16x8;
typedef __attribute__((ext_vector_type(4))) float f32x4;

#define DIM      256
#define KCODES   4096
#define Q_OFF    16777216
#define L_OFF    16842752
#define EB_OFF   8388608
#define XN_OFF   8912896
#define EMAX_OFF 8978432
#define BEST_OFF 8978440
#define CAP      12288

__device__ __forceinline__ u16 f2bf(float f) {           // RNE f32->bf16 (no NaN inputs)
    u32 u = __float_as_uint(f);
    return (u16)((u + 0x7FFFu + ((u >> 16) & 1u)) >> 16);
}

// exact serial-ascending fmaf dot + score + packed atomicMin (R1-proven semantics)
__device__ __forceinline__ void rescore(int row, int code,
                                        const float* __restrict__ x,
                                        const float* __restrict__ emb,
                                        const float* __restrict__ xnorm,
                                        u64* __restrict__ best) {
    const float* xr = x + row * DIM;
    const float* er = emb + code * DIM;
    float acc = 0.f;
    #pragma unroll 8
    for (int d = 0; d < DIM; ++d) acc = fmaf(xr[d], er[d], acc);
    float sc = fmaf(-2.f, acc, xnorm[row]);
    u32 ub = __float_as_uint(sc);
    u32 key = (ub & 0x80000000u) ? ~ub : (ub | 0x80000000u);   // monotone float->u32
    atomicMin(best + row, ((u64)key << 32) | (u32)code);
}

// ---------------------------------------------------------------------------
__global__ void k_init(float* __restrict__ out) {
    int g = blockIdx.x * 256 + threadIdx.x;            // 65536
    ((u64*)(out + BEST_OFF))[g] = ~0ULL;
    if (g == 0) { out[EMAX_OFF] = 0.f; out[L_OFF] = 0.f; }
}

__global__ void k_conv(const float* __restrict__ x, u16* __restrict__ xb) {
    int g = blockIdx.x * 256 + threadIdx.x;            // 2,097,152 (8 floats each)
    const float4* p = (const float4*)x + g * 2;
    float4 a = p[0], b = p[1];
    uint4 o;
    o.x = (u32)f2bf(a.x) | ((u32)f2bf(a.y) << 16);
    o.y = (u32)f2bf(a.z) | ((u32)f2bf(a.w) << 16);
    o.z = (u32)f2bf(b.x) | ((u32)f2bf(b.y) << 16);
    o.w = (u32)f2bf(b.z) | ((u32)f2bf(b.w) << 16);
    ((uint4*)xb)[g] = o;
}

__global__ void k_conve(const float* __restrict__ e, u16* __restrict__ eb,
                        float* __restrict__ out) {
    int g = blockIdx.x * 256 + threadIdx.x;            // 131,072 (8 floats each)
    const float4* p = (const float4*)e + g * 2;
    float4 a = p[0], b = p[1];
    uint4 o;
    o.x = (u32)f2bf(a.x) | ((u32)f2bf(a.y) << 16);
    o.y = (u32)f2bf(a.z) | ((u32)f2bf(a.w) << 16);
    o.z = (u32)f2bf(b.x) | ((u32)f2bf(b.y) << 16);
    o.w = (u32)f2bf(b.z) | ((u32)f2bf(b.w) << 16);
    ((uint4*)eb)[g] = o;
    float s8 = a.x*a.x + a.y*a.y + a.z*a.z + a.w*a.w
             + b.x*b.x + b.y*b.y + b.z*b.z + b.w*b.w;  // row = g>>5 (32 lanes/row)
    #pragma unroll
    for (int off = 1; off < 32; off <<= 1) s8 += __shfl_xor(s8, off, 64);
    if ((threadIdx.x & 31) == 0)
        atomicMax((int*)(out + EMAX_OFF), __float_as_int(s8));  // >=0: int order ok
}

// AVX2-tree row norm, 8 lanes/row (bit-identical to R1's k_prep)
__global__ void k_prep(const float* __restrict__ x, float* __restrict__ out) {
    int g = blockIdx.x * 256 + threadIdx.x;            // 524,288
    int row = g >> 3, l = g & 7;
    const float* xr = x + row * DIM;
    float p = 0.f;
    #pragma unroll
    for (int i = 0; i < 32; ++i) { float v = xr[i*8 + l]; p = fmaf(v, v, p); }
    float q = p + __shfl_down(p, 4, 64);
    float r = q + __shfl_down(q, 2, 64);
    float s = r + __shfl_down(r, 1, 64);
    if (l == 0) out[XN_OFF + row] = s;
}

// ---------------------------------------------------------------------------
// Fused MFMA filter + candidate collection + exact rescore.
// 256 blocks x 512 thr (8 waves). Wave w owns rows [blk*256 + w*32, +32), K=256 in regs.
// Loop 128 code-tiles of 32; B tile 16KB double-buffered swizzled LDS.
// ---------------------------------------------------------------------------
__launch_bounds__(512, 2)
__global__ void k_vq(const u16* __restrict__ xb, const u16* __restrict__ eb,
                     const float* __restrict__ x, const float* __restrict__ emb,
                     const float* __restrict__ xnorm, const float* __restrict__ emax2,
                     u64* __restrict__ best) {
    __shared__ u16 Bt[2][32 * DIM];        // 2 x 16KB
    __shared__ u32 list[CAP];              // 48KB
    __shared__ u32 cnt, ovf;

    const int t = threadIdx.x, w = t >> 6, l = t & 63;
    const int brow = blockIdx.x * 256, lrow0 = w * 32;
    if (t == 0) { cnt = 0u; ovf = 0u; }

    // A fragments in registers: frag[s][mf]: row = lrow0+mf*16+(l&15), k = s*32+(l>>4)*8
    bf16x8 afr[8][2];
    #pragma unroll
    for (int s = 0; s < 8; ++s)
        #pragma unroll
        for (int mf = 0; mf < 2; ++mf)
            afr[s][mf] = *(const bf16x8*)(xb + (brow + lrow0 + mf*16 + (l & 15)) * DIM
                                             + s*32 + ((l >> 4) << 3));
    float xn[8], m[8], T[8];
    {
        float eM = sqrtf(emax2[0]);
        #pragma unroll
        for (int mf = 0; mf < 2; ++mf)
            #pragma unroll
            for (int r = 0; r < 4; ++r) {
                int slot = mf*4 + r;
                float v = xnorm[brow + lrow0 + mf*16 + ((l >> 4) << 2) + r];
                xn[slot] = v;
                T[slot]  = 4.f * (2.f * 0.009f * sqrtf(v) * eM + 2.0e-4f);
                m[slot]  = FLT_MAX;
            }
    }

    // stage tile 0 (swizzle: u16 idx = c*256 + ((q*8) ^ ((c&7)<<3)), unit=8 bf16)
    {
        int c = t >> 4, qp = (t & 15) * 2;
        const uint4* g = (const uint4*)(eb + c * DIM + qp * 8);
        uint4 u0 = g[0], u1 = g[1];
        *(uint4*)&Bt[0][c*256 + (( qp   *8) ^ ((c & 7) << 3))] = u0;
        *(uint4*)&Bt[0][c*256 + (((qp+1)*8) ^ ((c & 7) << 3))] = u1;
    }
    __syncthreads();

    for (int nt = 0; nt < 128; ++nt) {
        const int buf = nt & 1;
        uint4 u0, u1;
        const int c = t >> 4, qp = (t & 15) * 2;
        if (nt < 127) {                      // T14: issue next-tile loads early
            const uint4* g = (const uint4*)(eb + ((nt+1)*32 + c) * DIM + qp * 8);
            u0 = g[0]; u1 = g[1];
        }
        // ---- MFMA: 2x2 frags x 8 K-steps ----
        f32x4 acc[2][2] = {};
        #pragma unroll
        for (int s = 0; s < 8; ++s) {
            const int q = s*4 + (l >> 4);
            const int c0 = (l & 15), c1 = 16 + (l & 15);
            bf16x8 b0 = *(const bf16x8*)&Bt[buf][c0*256 + ((q*8) ^ ((c0 & 7) << 3))];
            bf16x8 b1 = *(const bf16x8*)&Bt[buf][c1*256 + ((q*8) ^ ((c1 & 7) << 3))];
            acc[0][0] = __builtin_amdgcn_mfma_f32_16x16x32_bf16(afr[s][0], b0, acc[0][0], 0,0,0);
            acc[1][0] = __builtin_amdgcn_mfma_f32_16x16x32_bf16(afr[s][1], b0, acc[1][0], 0,0,0);
            acc[0][1] = __builtin_amdgcn_mfma_f32_16x16x32_bf16(afr[s][0], b1, acc[0][1], 0,0,0);
            acc[1][1] = __builtin_amdgcn_mfma_f32_16x16x32_bf16(afr[s][1], b1, acc[1][1], 0,0,0);
        }
        // ---- epilogue: scores, running lane-min, collect ----
        float sc[2][2][4];
        #pragma unroll
        for (int mf = 0; mf < 2; ++mf)
            #pragma unroll
            for (int nf = 0; nf < 2; ++nf)
                #pragma unroll
                for (int r = 0; r < 4; ++r) {
                    float v = fmaf(-2.f, acc[mf][nf][r], xn[mf*4 + r]);
                    sc[mf][nf][r] = v;
                    m[mf*4 + r] = fminf(m[mf*4 + r], v);
                }
        if (nt & 1) {                        // periodic 16-lane row-min sync
            #pragma unroll
            for (int slot = 0; slot < 8; ++slot)
                #pragma unroll
                for (int off = 1; off < 16; off <<= 1)
                    m[slot] = fminf(m[slot], __shfl_xor(m[slot], off, 64));
        }
        #pragma unroll
        for (int mf = 0; mf < 2; ++mf)
            #pragma unroll
            for (int nf = 0; nf < 2; ++nf)
                #pragma unroll
                for (int r = 0; r < 4; ++r)
                    if (sc[mf][nf][r] <= m[mf*4 + r] + T[mf*4 + r]) {
                        u32 e = ((u32)(lrow0 + mf*16 + ((l >> 4) << 2) + r) << 16)
                              | (u32)(nt*32 + nf*16 + (l & 15));
                        u32 pos = atomicAdd(&cnt, 1u);
                        if (pos < CAP) list[pos] = e;
                        else if (pos == CAP) ovf = 1u;
                    }
        if (nt < 127) {                      // write next tile, then one barrier
            *(uint4*)&Bt[buf ^ 1][c*256 + (( qp   *8) ^ ((c & 7) << 3))] = u0;
            *(uint4*)&Bt[buf ^ 1][c*256 + (((qp+1)*8) ^ ((c & 7) << 3))] = u1;
        }
        __syncthreads();
    }

    // ---- batched exact rescore ----
    u32 n = cnt;
    if (ovf || n > CAP) {                    // safety net (never expected)
        for (u32 p = t; p < 256u * 4096u; p += 512u)
            rescore(brow + (int)(p >> 12), (int)(p & 4095u), x, emb, xnorm, best);
    } else {
        for (u32 i = t; i < n; i += 512u) {
            u32 e = list[i];
            rescore(brow + (int)(e >> 16), (int)(e & 0xFFFFu), x, emb, xnorm, best);
        }
    }
}

__global__ void k_indices(const u64* __restrict__ best, float* __restrict__ idxf) {
    int g = blockIdx.x * 256 + threadIdx.x;            // 65536
    idxf[g] = (float)(u32)(best[g] & 0xFFFFFFFFu);
}

// ---------------------------------------------------------------------------
// quantized_st = x + (q-x); loss accumulation (unchanged, R1-proven)
// ---------------------------------------------------------------------------
__global__ void k_output(const float* __restrict__ x, const float* __restrict__ emb,
                         const float* __restrict__ idx_f, float* __restrict__ out) {
    const int t = blockIdx.x * 256 + threadIdx.x;
    float lsum = 0.f;
    #pragma unroll
    for (int c = 0; c < 8; ++c) {
        int f4  = c * (2048*256) + t;
        int row = f4 >> 6;
        int c4  = f4 & 63;
        int idx = (int)idx_f[Q_OFF + row];
        float4 q  = ((const float4*)emb)[idx*64 + c4];
        float4 xv = ((const float4*)x)[f4];
        float4 o; float d;
        d = q.x - xv.x; o.x = xv.x + d; lsum = fmaf(d,d,lsum);
        d = q.y - xv.y; o.y = xv.y + d; lsum = fmaf(d,d,lsum);
        d = q.z - xv.z; o.z = xv.z + d; lsum = fmaf(d,d,lsum);
        d = q.w - xv.w; o.w = xv.w + d; lsum = fmaf(d,d,lsum);
        ((float4*)out)[f4] = o;
    }
    #pragma unroll
    for (int off = 32; off > 0; off >>= 1) lsum += __shfl_down(lsum, off, 64);
    __shared__ float wsum[4];
    if ((threadIdx.x & 63) == 0) wsum[threadIdx.x >> 6] = lsum;
    __syncthreads();
    if (threadIdx.x == 0)
        atomicAdd(&out[L_OFF], (wsum[0]+wsum[1]) + (wsum[2]+wsum[3]));
}

__global__ void k_final(float* __restrict__ out) {
    if (threadIdx.x == 0 && blockIdx.x == 0) {
        float m = out[L_OFF] * (1.f/16777216.f);
        out[L_OFF] = m + 0.25f * m;
    }
}

extern "C" void kernel_launch(void* const* d_in, const int* in_sizes, int n_in,
                              void* d_out, int out_size, void* d_ws, size_t ws_size,
                              hipStream_t stream) {
    const float* x   = (const float*)d_in[0];
    const float* emb = (const float*)d_in[1];
    float* out = (float*)d_out;
    u16* xb = (u16*)out;
    u16* eb = (u16*)(out + EB_OFF);
    u64* best = (u64*)(out + BEST_OFF);

    hipLaunchKernelGGL(k_init,    dim3(256),  dim3(256), 0, stream, out);
    hipLaunchKernelGGL(k_conv,    dim3(8192), dim3(256), 0, stream, x, xb);
    hipLaunchKernelGGL(k_conve,   dim3(512),  dim3(256), 0, stream, emb, eb, out);
    hipLaunchKernelGGL(k_prep,    dim3(2048), dim3(256), 0, stream, x, out);
    hipLaunchKernelGGL(k_vq,      dim3(256),  dim3(512), 0, stream,
                       xb, eb, x, emb, out + XN_OFF, out + EMAX_OFF, best);
    hipLaunchKernelGGL(k_indices, dim3(256),  dim3(256), 0, stream, best, out + Q_OFF);
    hipLaunchKernelGGL(k_output,  dim3(2048), dim3(256), 0, stream, x, emb, out, out);
    hipLaunchKernelGGL(k_final,   dim3(1),    dim3(1),   0, stream, out);
}

// Round 5
// 917.120 us; speedup vs baseline: 57.4215x; 57.4215x over previous
//
#include <hip/hip_runtime.h>
#include <math.h>
#include <float.h>

// VQ-VAE VectorQuantizer forward, MI355X (gfx950).
// R5: bf16-MFMA filter (seed-min phase + collect phase) + exact fp32 rescore.
//   x: [16,4096,256] f32 (N=65536 rows), embedding: [4096,256] f32 (K=4096).
//   out: [0,16777216) quantized_st | [Q_OFF,+65536) indices(float) | [L_OFF] loss
//
// R4 bug fixed: collection was seeded at FLT_MAX -> tile 0 collected everything
// -> CAP overflow -> brute fallback everywhere (52 ms, 8 GiB atomics). Now a
// 16-tile seed phase converges the per-row min BEFORE any collection.
//
// Exactness: reference score bits = fl(xnorm - 2*serial_dot) (R1-proven, absmax 0.0).
// bf16 path error: |s~-s| <= 2*(2^-8*2.01*||x||*eM) + slop ~= 0.016*||x||*eM.
// T = 0.05*||x||*eM + 5e-4 >= 2E  => true argmin (and all ties) always collected;
// exact serial-fmaf rescore + packed (score,idx) atomicMin in LDS reproduces
// argmin-with-lowest-index ties.
//
// Scratch inside out[0..16.7M) (overwritten by k_output at the end):
//   xb bf16 @0 | eb bf16 @EB_OFF | xnorm @XN_OFF | emax2 @EMAX_OFF

typedef unsigned int u32; typedef unsigned long long u64; typedef unsigned short u16;
typedef __attribute__((ext_vector_type(8))) short bf16x8;
typedef __attribute__((ext_vector_type(4))) float f32x4;

#define DIM      256
#define Q_OFF    16777216
#define L_OFF    16842752
#define EB_OFF   8388608
#define XN_OFF   8912896
#define EMAX_OFF 8978432
#define CAP      10240
#define NTILES   128
#define SEED     16

__device__ __forceinline__ u16 f2bf(float f) {           // RNE f32->bf16
    u32 u = __float_as_uint(f);
    return (u16)((u + 0x7FFFu + ((u >> 16) & 1u)) >> 16);
}

// exact serial-ascending fmaf dot + score + packed atomicMin into LDS best
__device__ __forceinline__ void rescore(int lrow, int code,
                                        const float* __restrict__ xr0,
                                        const float* __restrict__ emb,
                                        const float* __restrict__ xn0,
                                        u64* __restrict__ bestL) {
    const float* xr = xr0 + lrow * DIM;
    const float* er = emb + code * DIM;
    float acc = 0.f;
    #pragma unroll 8
    for (int d = 0; d < DIM; ++d) acc = fmaf(xr[d], er[d], acc);
    float sc = fmaf(-2.f, acc, xn0[lrow]);
    u32 ub = __float_as_uint(sc);
    u32 key = (ub & 0x80000000u) ? ~ub : (ub | 0x80000000u);   // monotone map
    atomicMin(&bestL[lrow], ((u64)key << 32) | (u32)code);
}

// ---------------------------------------------------------------------------
__global__ void k_init(float* __restrict__ out) {
    out[EMAX_OFF] = 0.f; out[L_OFF] = 0.f;
}

__global__ void k_conv(const float* __restrict__ x, u16* __restrict__ xb) {
    int g = blockIdx.x * 256 + threadIdx.x;            // 2,097,152 x 8 floats
    const float4* p = (const float4*)x + g * 2;
    float4 a = p[0], b = p[1];
    uint4 o;
    o.x = (u32)f2bf(a.x) | ((u32)f2bf(a.y) << 16);
    o.y = (u32)f2bf(a.z) | ((u32)f2bf(a.w) << 16);
    o.z = (u32)f2bf(b.x) | ((u32)f2bf(b.y) << 16);
    o.w = (u32)f2bf(b.z) | ((u32)f2bf(b.w) << 16);
    ((uint4*)xb)[g] = o;
}

__global__ void k_conve(const float* __restrict__ e, u16* __restrict__ eb,
                        float* __restrict__ out) {
    int g = blockIdx.x * 256 + threadIdx.x;            // 131,072 x 8 floats
    const float4* p = (const float4*)e + g * 2;
    float4 a = p[0], b = p[1];
    uint4 o;
    o.x = (u32)f2bf(a.x) | ((u32)f2bf(a.y) << 16);
    o.y = (u32)f2bf(a.z) | ((u32)f2bf(a.w) << 16);
    o.z = (u32)f2bf(b.x) | ((u32)f2bf(b.y) << 16);
    o.w = (u32)f2bf(b.z) | ((u32)f2bf(b.w) << 16);
    ((uint4*)eb)[g] = o;
    float s8 = a.x*a.x + a.y*a.y + a.z*a.z + a.w*a.w
             + b.x*b.x + b.y*b.y + b.z*b.z + b.w*b.w;  // row = g>>5
    #pragma unroll
    for (int off = 1; off < 32; off <<= 1) s8 += __shfl_xor(s8, off, 64);
    if ((threadIdx.x & 31) == 0)
        atomicMax((int*)(out + EMAX_OFF), __float_as_int(s8));  // >=0 bits-order
}

// AVX2-tree row norm, 8 lanes/row (bit-identical to R1)
__global__ void k_prep(const float* __restrict__ x, float* __restrict__ out) {
    int g = blockIdx.x * 256 + threadIdx.x;            // 524,288
    int row = g >> 3, l = g & 7;
    const float* xr = x + row * DIM;
    float p = 0.f;
    #pragma unroll
    for (int i = 0; i < 32; ++i) { float v = xr[i*8 + l]; p = fmaf(v, v, p); }
    float q = p + __shfl_down(p, 4, 64);
    float r = q + __shfl_down(q, 2, 64);
    float s = r + __shfl_down(r, 1, 64);
    if (l == 0) out[XN_OFF + row] = s;
}

// ---------------------------------------------------------------------------
// Fused MFMA filter: seed-min (16 tiles) -> collect (128 tiles) -> exact rescore.
// 256 blocks x 512 thr (8 waves); wave w owns rows [blk*256 + w*32, +32).
// B tiles (32 codes x 256 d bf16, 16KB) double-buffered, XOR-swizzled LDS.
// ---------------------------------------------------------------------------
__launch_bounds__(512, 2)
__global__ void k_vq(const u16* __restrict__ xb, const u16* __restrict__ eb,
                     const float* __restrict__ x, const float* __restrict__ emb,
                     const float* __restrict__ xnorm, const float* __restrict__ emax2,
                     float* __restrict__ idxf) {
    __shared__ u16 Bt[2][32 * DIM];        // 32 KB
    __shared__ u32 list[CAP];              // 40 KB
    __shared__ u64 bestL[256];             // 2 KB
    __shared__ u32 cnt, ovf;

    const int t = threadIdx.x, w = t >> 6, l = t & 63;
    const int brow = blockIdx.x * 256, lrow0 = w * 32;
    if (t == 0) { cnt = 0u; ovf = 0u; }
    if (t < 256) bestL[t] = ~0ULL;

    // A fragments: afr[s][mf]: row = lrow0+mf*16+(l&15), k = s*32+(l>>4)*8
    bf16x8 afr[8][2];
    #pragma unroll
    for (int s = 0; s < 8; ++s)
        #pragma unroll
        for (int mf = 0; mf < 2; ++mf)
            afr[s][mf] = *(const bf16x8*)(xb + (brow + lrow0 + mf*16 + (l & 15)) * DIM
                                             + s*32 + ((l >> 4) << 3));
    float xn[8], m[8], T[8];
    {
        float eM = sqrtf(emax2[0]);
        #pragma unroll
        for (int mf = 0; mf < 2; ++mf)
            #pragma unroll
            for (int r = 0; r < 4; ++r) {
                int slot = mf*4 + r;
                float v = xnorm[brow + lrow0 + mf*16 + ((l >> 4) << 2) + r];
                xn[slot] = v;
                T[slot]  = 0.05f * sqrtf(v) * eM + 5.0e-4f;
                m[slot]  = FLT_MAX;
            }
    }

    const int c = t >> 4, qp = (t & 15) * 2, cs = (c & 7) << 3;
    uint4 u0, u1;

    #define STAGE_LOAD(NT) { const uint4* g_ = (const uint4*)(eb + ((NT)*32 + c) * DIM + qp * 8); \
                             u0 = g_[0]; u1 = g_[1]; }
    #define STAGE_WRITE(B) { *(uint4*)&Bt[B][c*256 + (( qp   *8) ^ cs)] = u0; \
                             *(uint4*)&Bt[B][c*256 + (((qp+1)*8) ^ cs)] = u1; }
    #define DO_MFMA(B, ACC) \
        _Pragma("unroll") \
        for (int s = 0; s < 8; ++s) { \
            const int q_ = s*4 + (l >> 4); \
            const int c0_ = (l & 15), c1_ = 16 + (l & 15); \
            bf16x8 b0 = *(const bf16x8*)&Bt[B][c0_*256 + ((q_*8) ^ ((c0_ & 7) << 3))]; \
            bf16x8 b1 = *(const bf16x8*)&Bt[B][c1_*256 + ((q_*8) ^ ((c1_ & 7) << 3))]; \
            ACC[0][0] = __builtin_amdgcn_mfma_f32_16x16x32_bf16(afr[s][0], b0, ACC[0][0], 0,0,0); \
            ACC[1][0] = __builtin_amdgcn_mfma_f32_16x16x32_bf16(afr[s][1], b0, ACC[1][0], 0,0,0); \
            ACC[0][1] = __builtin_amdgcn_mfma_f32_16x16x32_bf16(afr[s][0], b1, ACC[0][1], 0,0,0); \
            ACC[1][1] = __builtin_amdgcn_mfma_f32_16x16x32_bf16(afr[s][1], b1, ACC[1][1], 0,0,0); \
        }

    // ================= seed phase: tiles 0..15, min only =================
    STAGE_LOAD(0) STAGE_WRITE(0)
    __syncthreads();
    #pragma unroll 1
    for (int nt = 0; nt < SEED; ++nt) {
        const int buf = nt & 1;
        STAGE_LOAD(nt + 1)                 // tile 16 exists; always prefetch
        f32x4 acc[2][2] = {};
        DO_MFMA(buf, acc)
        #pragma unroll
        for (int mf = 0; mf < 2; ++mf)
            #pragma unroll
            for (int nf = 0; nf < 2; ++nf)
                #pragma unroll
                for (int r = 0; r < 4; ++r)
                    m[mf*4 + r] = fminf(m[mf*4 + r], fmaf(-2.f, acc[mf][nf][r], xn[mf*4 + r]));
        STAGE_WRITE(buf ^ 1)
        __syncthreads();
    }
    // row min over 512 seed codes: reduce across the 16 lanes sharing each row
    #pragma unroll
    for (int slot = 0; slot < 8; ++slot)
        #pragma unroll
        for (int off = 1; off < 16; off <<= 1)
            m[slot] = fminf(m[slot], __shfl_xor(m[slot], off, 64));

    // ================= main phase: tiles 0..127, collect =================
    STAGE_LOAD(0) STAGE_WRITE(0)
    __syncthreads();
    #pragma unroll 1
    for (int nt = 0; nt < NTILES; ++nt) {
        const int buf = nt & 1;
        if (nt < NTILES - 1) STAGE_LOAD(nt + 1)
        f32x4 acc[2][2] = {};
        DO_MFMA(buf, acc)
        #pragma unroll
        for (int mf = 0; mf < 2; ++mf)
            #pragma unroll
            for (int nf = 0; nf < 2; ++nf)
                #pragma unroll
                for (int r = 0; r < 4; ++r) {
                    const int slot = mf*4 + r;
                    float v = fmaf(-2.f, acc[mf][nf][r], xn[slot]);
                    if (v <= m[slot] + T[slot]) {
                        u32 e = ((u32)(lrow0 + mf*16 + ((l >> 4) << 2) + r) << 16)
                              | (u32)(nt*32 + nf*16 + (l & 15));
                        u32 pos = atomicAdd(&cnt, 1u);
                        if (pos < CAP) list[pos] = e;
                        else if (pos == CAP) ovf = 1u;
                    }
                    m[slot] = fminf(m[slot], v);       // tighten for later tiles
                }
        if (nt < NTILES - 1) STAGE_WRITE(buf ^ 1)
        __syncthreads();
    }

    // ================= exact rescore of candidates =================
    const float* xr0 = x + brow * DIM;
    const float* xn0 = xnorm + brow;
    if (ovf) {                               // mathematically unreachable (T >= 2E)
        for (u32 p = t; p < 256u * 4096u; p += 512u)
            rescore((int)(p >> 12), (int)(p & 4095u), xr0, emb, xn0, bestL);
    } else {
        u32 n = cnt;
        for (u32 i = t; i < n; i += 512u) {
            u32 e = list[i];
            rescore((int)(e >> 16), (int)(e & 0xFFFFu), xr0, emb, xn0, bestL);
        }
    }
    __syncthreads();
    if (t < 256) idxf[brow + t] = (float)(u32)(bestL[t] & 0xFFFFFFFFu);
}

// ---------------------------------------------------------------------------
// quantized_st = x + (q-x); loss accumulation (unchanged, R1-proven)
// ---------------------------------------------------------------------------
__global__ void k_output(const float* __restrict__ x, const float* __restrict__ emb,
                         const float* __restrict__ idx_f, float* __restrict__ out) {
    const int t = blockIdx.x * 256 + threadIdx.x;
    float lsum = 0.f;
    #pragma unroll
    for (int c = 0; c < 8; ++c) {
        int f4  = c * (2048*256) + t;
        int row = f4 >> 6;
        int c4  = f4 & 63;
        int idx = (int)idx_f[Q_OFF + row];
        float4 q  = ((const float4*)emb)[idx*64 + c4];
        float4 xv = ((const float4*)x)[f4];
        float4 o; float d;
        d = q.x - xv.x; o.x = xv.x + d; lsum = fmaf(d,d,lsum);
        d = q.y - xv.y; o.y = xv.y + d; lsum = fmaf(d,d,lsum);
        d = q.z - xv.z; o.z = xv.z + d; lsum = fmaf(d,d,lsum);
        d = q.w - xv.w; o.w = xv.w + d; lsum = fmaf(d,d,lsum);
        ((float4*)out)[f4] = o;
    }
    #pragma unroll
    for (int off = 32; off > 0; off >>= 1) lsum += __shfl_down(lsum, off, 64);
    __shared__ float wsum[4];
    if ((threadIdx.x & 63) == 0) wsum[threadIdx.x >> 6] = lsum;
    __syncthreads();
    if (threadIdx.x == 0)
        atomicAdd(&out[L_OFF], (wsum[0]+wsum[1]) + (wsum[2]+wsum[3]));
}

__global__ void k_final(float* __restrict__ out) {
    if (threadIdx.x == 0 && blockIdx.x == 0) {
        float m = out[L_OFF] * (1.f/16777216.f);
        out[L_OFF] = m + 0.25f * m;
    }
}

extern "C" void kernel_launch(void* const* d_in, const int* in_sizes, int n_in,
                              void* d_out, int out_size, void* d_ws, size_t ws_size,
                              hipStream_t stream) {
    const float* x   = (const float*)d_in[0];
    const float* emb = (const float*)d_in[1];
    float* out = (float*)d_out;
    u16* xb = (u16*)out;
    u16* eb = (u16*)(out + EB_OFF);

    hipLaunchKernelGGL(k_init,   dim3(1),    dim3(1),   0, stream, out);
    hipLaunchKernelGGL(k_conv,   dim3(8192), dim3(256), 0, stream, x, xb);
    hipLaunchKernelGGL(k_conve,  dim3(512),  dim3(256), 0, stream, emb, eb, out);
    hipLaunchKernelGGL(k_prep,   dim3(2048), dim3(256), 0, stream, x, out);
    hipLaunchKernelGGL(k_vq,     dim3(256),  dim3(512), 0, stream,
                       xb, eb, x, emb, out + XN_OFF, out + EMAX_OFF, out + Q_OFF);
    hipLaunchKernelGGL(k_output, dim3(2048), dim3(256), 0, stream, x, emb, out, out);
    hipLaunchKernelGGL(k_final,  dim3(1),    dim3(1),   0, stream, out);
}

// Round 6
// 527.575 us; speedup vs baseline: 99.8199x; 1.7384x over previous
//
#include <hip/hip_runtime.h>
#include <math.h>
#include <float.h>

// VQ-VAE VectorQuantizer forward, MI355X (gfx950). R6.
//   x: [16,4096,256] f32 (N=65536 rows), embedding: [4096,256] f32 (K=4096).
//   out: [0,16777216) quantized_st | [Q_OFF,+65536) indices(float) | [L_OFF] loss
//
// R5 post-mortem: rescore (uncoalesced scalar loads, ~37 cands/row from a
// 512-code seed min) dominated at ~700 µs; LDS b128-per-2-MFMA was secondary.
// R6: (1) k_min computes the TRUE bf16 row max-dot over all codes (min score
// <=> max dot exactly, fl(xn-2d) monotone), k_collect windows on it -> ~6/row;
// (2) 4 row-frags/wave -> 4 MFMA per ds_read_b128; (3) float4 rescore (serial
// fmaf chain preserved bit-exactly); (4) grid 512 = 2 blocks/CU.
//
// Exactness (R1/R5-proven): reference score bits = fl(xnorm - 2*serial_dot);
// AVX2-tree xnorm; ties -> lowest index via packed (key|idx) u64 atomicMin.
// bf16 filter window Wd = 0.025*||x||*eM + 5e-4 (= R5's passing T in dot
// units, includes fl-collapse ulp(256)~3e-5) guarantees the argmin and all
// its score-ties are collected; exact fp32 rescore decides.
//
// Scratch inside out[0..16.7M) (overwritten by k_output at the end):
//   xb bf16 @0 | eb bf16 @EB_OFF | xnorm @XN_OFF | emax2 @EMAX_OFF
//   rowdotmax u32 @RM_OFF | best u64 @BEST_OFF

typedef unsigned int u32; typedef unsigned long long u64; typedef unsigned short u16;
typedef __attribute__((ext_vector_type(8))) short bf16x8;
typedef __attribute__((ext_vector_type(4))) float f32x4;

#define DIM      256
#define Q_OFF    16777216
#define L_OFF    16842752
#define EB_OFF   8388608
#define XN_OFF   8912896
#define EMAX_OFF 8978432
#define RM_OFF   8978440
#define BEST_OFF 9043976
#define CAP      3072

__device__ __forceinline__ u16 f2bf(float f) {           // RNE f32->bf16
    u32 u = __float_as_uint(f);
    return (u16)((u + 0x7FFFu + ((u >> 16) & 1u)) >> 16);
}
__device__ __forceinline__ u32 fkey(float f) {           // monotone f32->u32
    u32 u = __float_as_uint(f);
    return (u & 0x80000000u) ? ~u : (u | 0x80000000u);
}
__device__ __forceinline__ float fdec(u32 k) {           // inverse of fkey
    return __uint_as_float((k & 0x80000000u) ? (k ^ 0x80000000u) : ~k);
}

// exact serial fmaf dot (float4 loads, same op sequence) + packed atomicMin
__device__ __forceinline__ void rescore(int grow, int code,
                                        const float* __restrict__ x,
                                        const float* __restrict__ emb,
                                        const float* __restrict__ xnorm,
                                        u64* __restrict__ best) {
    const float4* xr = (const float4*)(x + grow * DIM);
    const float4* er = (const float4*)(emb + code * DIM);
    float acc = 0.f;
    #pragma unroll 8
    for (int q = 0; q < 64; ++q) {
        float4 a = xr[q], b = er[q];
        acc = fmaf(a.x, b.x, acc); acc = fmaf(a.y, b.y, acc);
        acc = fmaf(a.z, b.z, acc); acc = fmaf(a.w, b.w, acc);
    }
    float sc = fmaf(-2.f, acc, xnorm[grow]);
    atomicMin(best + grow, ((u64)fkey(sc) << 32) | (u32)code);
}

// ---------------------------------------------------------------------------
__global__ void k_init(float* __restrict__ out) {
    int g = blockIdx.x * 256 + threadIdx.x;              // 65536
    ((u32*)(out + RM_OFF))[g] = 0u;                      // key 0 < all real keys
    ((u64*)(out + BEST_OFF))[g] = ~0ULL;
    if (g == 0) { out[EMAX_OFF] = 0.f; out[L_OFF] = 0.f; }
}

__global__ void k_conv(const float* __restrict__ x, u16* __restrict__ xb) {
    int g = blockIdx.x * 256 + threadIdx.x;              // 2,097,152 x 8 floats
    const float4* p = (const float4*)x + g * 2;
    float4 a = p[0], b = p[1];
    uint4 o;
    o.x = (u32)f2bf(a.x) | ((u32)f2bf(a.y) << 16);
    o.y = (u32)f2bf(a.z) | ((u32)f2bf(a.w) << 16);
    o.z = (u32)f2bf(b.x) | ((u32)f2bf(b.y) << 16);
    o.w = (u32)f2bf(b.z) | ((u32)f2bf(b.w) << 16);
    ((uint4*)xb)[g] = o;
}

__global__ void k_conve(const float* __restrict__ e, u16* __restrict__ eb,
                        float* __restrict__ out) {
    int g = blockIdx.x * 256 + threadIdx.x;              // 131,072 x 8 floats
    const float4* p = (const float4*)e + g * 2;
    float4 a = p[0], b = p[1];
    uint4 o;
    o.x = (u32)f2bf(a.x) | ((u32)f2bf(a.y) << 16);
    o.y = (u32)f2bf(a.z) | ((u32)f2bf(a.w) << 16);
    o.z = (u32)f2bf(b.x) | ((u32)f2bf(b.y) << 16);
    o.w = (u32)f2bf(b.z) | ((u32)f2bf(b.w) << 16);
    ((uint4*)eb)[g] = o;
    float s8 = a.x*a.x + a.y*a.y + a.z*a.z + a.w*a.w
             + b.x*b.x + b.y*b.y + b.z*b.z + b.w*b.w;    // row = g>>5
    #pragma unroll
    for (int off = 1; off < 32; off <<= 1) s8 += __shfl_xor(s8, off, 64);
    if ((threadIdx.x & 31) == 0)
        atomicMax((int*)(out + EMAX_OFF), __float_as_int(s8));
}

// AVX2-tree row norm, 8 lanes/row (bit-identical to R1)
__global__ void k_prep(const float* __restrict__ x, float* __restrict__ out) {
    int g = blockIdx.x * 256 + threadIdx.x;              // 524,288
    int row = g >> 3, l = g & 7;
    const float* xr = x + row * DIM;
    float p = 0.f;
    #pragma unroll
    for (int i = 0; i < 32; ++i) { float v = xr[i*8 + l]; p = fmaf(v, v, p); }
    float q = p + __shfl_down(p, 4, 64);
    float r = q + __shfl_down(q, 2, 64);
    float s = r + __shfl_down(r, 1, 64);
    if (l == 0) out[XN_OFF + row] = s;
}

// ---------------------------------------------------------------------------
// Shared tiling for k_min/k_collect: 512 blocks x 256 thr (4 waves).
// Block b: rows [ (b&255)*256, +256 ), codes [ (b>>8)*2048, +2048 ) in 64
// tiles of 32. Wave w: rows w*64..w*64+63 as 4 frags. B tile dbuf in LDS.
// Frag maps (R5-proven): A row=l&15, k=s*32+(l>>4)*8; B col=l&15(+16), same k;
// C col=l&15, row=(l>>4)*4+r.
// ---------------------------------------------------------------------------
#define TILE_COMMON_SETUP \
    const int t = threadIdx.x, w = t >> 6, l = t & 63; \
    const int brow = (blockIdx.x & 255) * 256, cbase = (blockIdx.x >> 8) * 2048; \
    const int wrow = brow + w * 64; \
    const int c = t >> 3, q0 = (t & 7) * 4, cs = (c & 7) << 3;

#define LOAD_AFRAGS \
    bf16x8 afr[8][4]; \
    _Pragma("unroll") \
    for (int s = 0; s < 8; ++s) \
        _Pragma("unroll") \
        for (int rf = 0; rf < 4; ++rf) \
            afr[s][rf] = *(const bf16x8*)(xb + (wrow + rf*16 + (l & 15)) * DIM \
                                             + s*32 + ((l >> 4) << 3));

#define STAGE_LOAD(NT) { \
    const uint4* g_ = (const uint4*)(eb + (cbase + (NT)*32 + c) * DIM + q0 * 8); \
    u0 = g_[0]; u1 = g_[1]; u2 = g_[2]; u3 = g_[3]; }

#define STAGE_WRITE(B) { \
    *(uint4*)&Bt[B][c*256 + (( q0   *8) ^ cs)] = u0; \
    *(uint4*)&Bt[B][c*256 + (((q0+1)*8) ^ cs)] = u1; \
    *(uint4*)&Bt[B][c*256 + (((q0+2)*8) ^ cs)] = u2; \
    *(uint4*)&Bt[B][c*256 + (((q0+3)*8) ^ cs)] = u3; }

#define DO_MFMA(B, ACC) \
    _Pragma("unroll") \
    for (int s = 0; s < 8; ++s) { \
        const int q_ = s*4 + (l >> 4); \
        const int c0_ = (l & 15), c1_ = 16 + (l & 15); \
        bf16x8 b0 = *(const bf16x8*)&Bt[B][c0_*256 + ((q_*8) ^ ((c0_ & 7) << 3))]; \
        bf16x8 b1 = *(const bf16x8*)&Bt[B][c1_*256 + ((q_*8) ^ ((c1_ & 7) << 3))]; \
        _Pragma("unroll") \
        for (int rf = 0; rf < 4; ++rf) { \
            ACC[rf][0] = __builtin_amdgcn_mfma_f32_16x16x32_bf16(afr[s][rf], b0, ACC[rf][0], 0,0,0); \
            ACC[rf][1] = __builtin_amdgcn_mfma_f32_16x16x32_bf16(afr[s][rf], b1, ACC[rf][1], 0,0,0); \
        } }

// ---------------- pass 1: true bf16 row max-dot --------------------------
__launch_bounds__(256, 2)
__global__ void k_min(const u16* __restrict__ xb, const u16* __restrict__ eb,
                      u32* __restrict__ rowdot) {
    __shared__ u16 Bt[2][32 * DIM];        // 32 KB
    TILE_COMMON_SETUP
    LOAD_AFRAGS
    float md[4][4];
    #pragma unroll
    for (int rf = 0; rf < 4; ++rf)
        #pragma unroll
        for (int r = 0; r < 4; ++r) md[rf][r] = -FLT_MAX;

    uint4 u0, u1, u2, u3;
    STAGE_LOAD(0) STAGE_WRITE(0)
    __syncthreads();
    #pragma unroll 1
    for (int nt = 0; nt < 64; ++nt) {
        const int buf = nt & 1;
        if (nt < 63) STAGE_LOAD(nt + 1)
        f32x4 acc[4][2] = {};
        DO_MFMA(buf, acc)
        #pragma unroll
        for (int rf = 0; rf < 4; ++rf)
            #pragma unroll
            for (int r = 0; r < 4; ++r)
                md[rf][r] = fmaxf(md[rf][r], fmaxf(acc[rf][0][r], acc[rf][1][r]));
        if (nt < 63) STAGE_WRITE(buf ^ 1)
        __syncthreads();
    }
    // reduce max across the 16 lanes sharing each row, then atomicMax global
    #pragma unroll
    for (int rf = 0; rf < 4; ++rf)
        #pragma unroll
        for (int r = 0; r < 4; ++r) {
            float v = md[rf][r];
            #pragma unroll
            for (int off = 1; off < 16; off <<= 1)
                v = fmaxf(v, __shfl_xor(v, off, 64));
            if ((l & 15) == 0)
                atomicMax(rowdot + wrow + rf*16 + ((l >> 4) << 2) + r, fkey(v));
        }
}

// ---------------- pass 2: collect within window + exact rescore ----------
__launch_bounds__(256, 2)
__global__ void k_collect(const u16* __restrict__ xb, const u16* __restrict__ eb,
                          const float* __restrict__ x, const float* __restrict__ emb,
                          const float* __restrict__ xnorm, const float* __restrict__ emax2,
                          const u32* __restrict__ rowdot, u64* __restrict__ best) {
    __shared__ u16 Bt[2][32 * DIM];        // 32 KB
    __shared__ u32 list[CAP];              // 12 KB
    __shared__ u32 cnt, ovf;
    TILE_COMMON_SETUP
    if (t == 0) { cnt = 0u; ovf = 0u; }
    LOAD_AFRAGS
    float dthr[4][4];
    {
        float eM = sqrtf(emax2[0]);
        #pragma unroll
        for (int rf = 0; rf < 4; ++rf)
            #pragma unroll
            for (int r = 0; r < 4; ++r) {
                int grow = wrow + rf*16 + ((l >> 4) << 2) + r;
                float dmax = fdec(rowdot[grow]);
                float Wd = 0.025f * sqrtf(xnorm[grow]) * eM + 5.0e-4f;
                dthr[rf][r] = dmax - Wd;
            }
    }
    __syncthreads();

    uint4 u0, u1, u2, u3;
    STAGE_LOAD(0) STAGE_WRITE(0)
    __syncthreads();
    #pragma unroll 1
    for (int nt = 0; nt < 64; ++nt) {
        const int buf = nt & 1;
        if (nt < 63) STAGE_LOAD(nt + 1)
        f32x4 acc[4][2] = {};
        DO_MFMA(buf, acc)
        #pragma unroll
        for (int rf = 0; rf < 4; ++rf)
            #pragma unroll
            for (int nf = 0; nf < 2; ++nf)
                #pragma unroll
                for (int r = 0; r < 4; ++r)
                    if (acc[rf][nf][r] >= dthr[rf][r]) {
                        u32 e = ((u32)(w*64 + rf*16 + ((l >> 4) << 2) + r) << 16)
                              | (u32)(cbase + nt*32 + nf*16 + (l & 15));
                        u32 pos = atomicAdd(&cnt, 1u);
                        if (pos < CAP) list[pos] = e;
                        else ovf = 1u;
                    }
        if (nt < 63) STAGE_WRITE(buf ^ 1)
        __syncthreads();
    }

    if (ovf) {                               // unreachable safety net
        for (u32 p = t; p < 256u * 2048u; p += 256u)
            rescore(brow + (int)(p >> 11), cbase + (int)(p & 2047u),
                    x, emb, xnorm, best);
    } else {
        u32 n = cnt;
        for (u32 i = t; i < n; i += 256u) {
            u32 e = list[i];
            rescore(brow + (int)(e >> 16), (int)(e & 0xFFFFu),
                    x, emb, xnorm, best);
        }
    }
}

__global__ void k_indices(const u64* __restrict__ best, float* __restrict__ idxf) {
    int g = blockIdx.x * 256 + threadIdx.x;              // 65536
    idxf[g] = (float)(u32)(best[g] & 0xFFFFFFFFu);
}

// ---------------------------------------------------------------------------
__global__ void k_output(const float* __restrict__ x, const float* __restrict__ emb,
                         const float* __restrict__ idx_f, float* __restrict__ out) {
    const int t = blockIdx.x * 256 + threadIdx.x;
    float lsum = 0.f;
    #pragma unroll
    for (int c = 0; c < 8; ++c) {
        int f4  = c * (2048*256) + t;
        int row = f4 >> 6;
        int c4  = f4 & 63;
        int idx = (int)idx_f[Q_OFF + row];
        float4 q  = ((const float4*)emb)[idx*64 + c4];
        float4 xv = ((const float4*)x)[f4];
        float4 o; float d;
        d = q.x - xv.x; o.x = xv.x + d; lsum = fmaf(d,d,lsum);
        d = q.y - xv.y; o.y = xv.y + d; lsum = fmaf(d,d,lsum);
        d = q.z - xv.z; o.z = xv.z + d; lsum = fmaf(d,d,lsum);
        d = q.w - xv.w; o.w = xv.w + d; lsum = fmaf(d,d,lsum);
        ((float4*)out)[f4] = o;
    }
    #pragma unroll
    for (int off = 32; off > 0; off >>= 1) lsum += __shfl_down(lsum, off, 64);
    __shared__ float wsum[4];
    if ((threadIdx.x & 63) == 0) wsum[threadIdx.x >> 6] = lsum;
    __syncthreads();
    if (threadIdx.x == 0)
        atomicAdd(&out[L_OFF], (wsum[0]+wsum[1]) + (wsum[2]+wsum[3]));
}

__global__ void k_final(float* __restrict__ out) {
    if (threadIdx.x == 0 && blockIdx.x == 0) {
        float m = out[L_OFF] * (1.f/16777216.f);
        out[L_OFF] = m + 0.25f * m;
    }
}

extern "C" void kernel_launch(void* const* d_in, const int* in_sizes, int n_in,
                              void* d_out, int out_size, void* d_ws, size_t ws_size,
                              hipStream_t stream) {
    const float* x   = (const float*)d_in[0];
    const float* emb = (const float*)d_in[1];
    float* out = (float*)d_out;
    u16* xb = (u16*)out;
    u16* eb = (u16*)(out + EB_OFF);
    u32* rowdot = (u32*)(out + RM_OFF);
    u64* best   = (u64*)(out + BEST_OFF);

    hipLaunchKernelGGL(k_init,    dim3(256),  dim3(256), 0, stream, out);
    hipLaunchKernelGGL(k_conv,    dim3(8192), dim3(256), 0, stream, x, xb);
    hipLaunchKernelGGL(k_conve,   dim3(512),  dim3(256), 0, stream, emb, eb, out);
    hipLaunchKernelGGL(k_prep,    dim3(2048), dim3(256), 0, stream, x, out);
    hipLaunchKernelGGL(k_min,     dim3(512),  dim3(256), 0, stream, xb, eb, rowdot);
    hipLaunchKernelGGL(k_collect, dim3(512),  dim3(256), 0, stream,
                       xb, eb, x, emb, out + XN_OFF, out + EMAX_OFF, rowdot, best);
    hipLaunchKernelGGL(k_indices, dim3(256),  dim3(256), 0, stream, best, out + Q_OFF);
    hipLaunchKernelGGL(k_output,  dim3(2048), dim3(256), 0, stream, x, emb, out, out);
    hipLaunchKernelGGL(k_final,   dim3(1),    dim3(1),   0, stream, out);
}